// Round 9
// baseline (13030.009 us; speedup 1.0000x reference)
//
#include <hip/hip_runtime.h>
#include <math.h>

// GreyBox rollout, round 11 (resubmit; previous bench was an infra failure —
// container died twice, no kernel signal). Wave-0 instruction diet (the only
// lever that has ever moved k4: r5 -16%, r6 -16%; all non-wave-0 changes
// <=2%).
//  - Fused LDS plane zb2[slot][comp][2] = (conv-chain word, base word):
//    quad's 2 per-step b32 reads -> 1 ds_read_b64 for TT=0..5 (TT=6,7 keep
//    split reads; base of next block is concurrently written by wave 2).
//    Conv writes even words, wave 2 writes odd words: word-disjoint.
//  - Split za chain: chain A seeded by chainP, chain B by baseP (kills the
//    seed-combine add, halves the serial FMA chain).
// All else identical to round 10 (dense fillers, LDS-lean waves 1/2/3).

#define T_STEPS 65536
#define SD 100
#define DT_F 0.01f

// ---------- helpers ----------
__device__ __forceinline__ float dpp_xor1_add(float x) {
  int v = __builtin_amdgcn_update_dpp(0, __float_as_int(x), 0xB1, 0xF, 0xF, true);
  return x + __int_as_float(v);
}
template <int PAT>
__device__ __forceinline__ float dppq(float x) {
  return __int_as_float(__builtin_amdgcn_update_dpp(0, __float_as_int(x), PAT, 0xF, 0xF, true));
}
__device__ __forceinline__ float tanh_fast(float x) {
  // tanh(x) = 1 - 2/(e^{2x}+1);  e^{2x} = exp2(x * 2/ln2)
  float e = __builtin_amdgcn_exp2f(x * 2.885390081777927f);
  return 1.f - 2.f * __builtin_amdgcn_rcpf(e + 1.f);
}
__device__ __forceinline__ float rdlane(float v, int l) {
  return __int_as_float(__builtin_amdgcn_readlane(__float_as_int(v), l));
}

// ---------- K0: setup (A^8, A^256, P_k=DT*W1A^k (k=16..23), G_k=DT*W1A^kW2
// (k=0..22), Q_i=A^{7-i}W2) ----------
__global__ __launch_bounds__(256, 1) void k0_setup(
    const float* __restrict__ A, const float* __restrict__ W1,
    const float* __restrict__ W2, float* __restrict__ A8o,
    float* __restrict__ A256o, float* __restrict__ Pws,
    float* __restrict__ Gws, float* __restrict__ Qws) {
  __shared__ __align__(16) float Al[10000];
  __shared__ __align__(16) float M0[10000];
  __shared__ __align__(16) float M1[10000];
  __shared__ __align__(16) float Pb[2][800];
  __shared__ __align__(16) float Vb[2][800];
  const int tid = threadIdx.x;
  for (int i = tid; i < 2500; i += 256) {
    ((float4*)Al)[i] = ((const float4*)A)[i];
    ((float4*)M0)[i] = ((const float4*)A)[i];
  }
  __syncthreads();
  // squarings: after s, result in ((s&1)?M0:M1). s=2 -> A^8, s=7 -> A^256.
  for (int s = 0; s < 8; ++s) {
    const float* src = (s & 1) ? M1 : M0;
    float* dst = (s & 1) ? M0 : M1;
    if (tid < 100) {
      float4 acc[25];
      #pragma unroll
      for (int i = 0; i < 25; ++i) acc[i] = make_float4(0.f, 0.f, 0.f, 0.f);
      for (int k = 0; k < 100; ++k) {
        float a = src[tid * 100 + k];
        const float4* rk = (const float4*)(src + k * 100);
        #pragma unroll
        for (int i = 0; i < 25; ++i) {
          float4 r4 = rk[i];
          acc[i].x = fmaf(a, r4.x, acc[i].x);
          acc[i].y = fmaf(a, r4.y, acc[i].y);
          acc[i].z = fmaf(a, r4.z, acc[i].z);
          acc[i].w = fmaf(a, r4.w, acc[i].w);
        }
      }
      #pragma unroll
      for (int i = 0; i < 25; ++i) ((float4*)(dst + tid * 100))[i] = acc[i];
    }
    __syncthreads();
    if (s == 2) for (int i = tid; i < 2500; i += 256) ((float4*)A8o)[i] = ((const float4*)dst)[i];
    if (s == 7) for (int i = tid; i < 2500; i += 256) ((float4*)A256o)[i] = ((const float4*)dst)[i];
    __syncthreads();
  }
  // P chain: P_0 = W1; P_k = P_{k-1} A. Store G_k (k<=22), P_k (16<=k<=23).
  for (int i = tid; i < 800; i += 256) Pb[0][i] = W1[i];
  __syncthreads();
  for (int k = 0; k < 24; ++k) {
    const float* Pc = Pb[k & 1];
    if (k <= 22 && tid < 64) {
      int i = tid >> 3, c = tid & 7;
      float g = 0.f;
      for (int l = 0; l < 100; ++l) g = fmaf(Pc[i * 100 + l], W2[l * 8 + c], g);
      Gws[k * 64 + i * 8 + c] = DT_F * g;
    }
    if (k >= 16) for (int i = tid; i < 800; i += 256) Pws[(k - 16) * 800 + i] = DT_F * Pc[i];
    __syncthreads();
    if (k < 23) {
      float* Pn = Pb[(k + 1) & 1];
      if (tid < 64) {
        int i = tid >> 3, cg = tid & 7;
        int c0 = cg * 13, c1 = c0 + 13 < 100 ? c0 + 13 : 100;
        for (int c = c0; c < c1; ++c) {
          float v = 0.f;
          for (int l = 0; l < 100; ++l) v = fmaf(Pc[i * 100 + l], Al[l * 100 + c], v);
          Pn[i * 100 + c] = v;
        }
      }
    }
    __syncthreads();
  }
  // V chain: V_0 = W2; V_j = A V_{j-1}. Q_i = V_{7-i} (unscaled).
  for (int i = tid; i < 800; i += 256) Vb[0][i] = W2[i];
  __syncthreads();
  for (int j = 0; j < 8; ++j) {
    const float* Vc = Vb[j & 1];
    for (int i = tid; i < 800; i += 256) Qws[(7 - j) * 800 + i] = Vc[i];
    __syncthreads();
    if (j < 7 && tid < 100) {
      float acc[8];
      #pragma unroll
      for (int c = 0; c < 8; ++c) acc[c] = 0.f;
      for (int l = 0; l < 100; ++l) {
        float av = Al[tid * 100 + l];
        #pragma unroll
        for (int c = 0; c < 8; ++c) acc[c] = fmaf(av, Vc[l * 8 + c], acc[c]);
      }
      float* dst = Vb[(j + 1) & 1] + tid * 8;
      #pragma unroll
      for (int c = 0; c < 8; ++c) dst[c] = acc[c];
    }
    __syncthreads();
  }
}

// ---------- rollout kernel (4 modes) ----------
// MODE 0: LIN local  (init 0, d = Bw w + u + DT b2)      -> SendOut
// MODE 1: LIN fix    (init X[b])                          -> out L, qbuf
// MODE 2: RHO local  (init 0, d = W2 h)                   -> SendOut
// MODE 3: RHO fix    (init XR[b])                         -> c = L+DT*rho, y
template <int MODE>
__global__ __launch_bounds__(256, 1) void k_rollout(
    const float* __restrict__ Amat, const float* __restrict__ Bw,
    const float* __restrict__ b2v, const float* __restrict__ ug,
    const float* __restrict__ wg, const float* __restrict__ W2,
    const float* __restrict__ hbufg, const float* __restrict__ W1,
    const float* __restrict__ b1v, const float* __restrict__ c0,
    const float* __restrict__ Xin, float* __restrict__ SendOut,
    float* __restrict__ Lc, float* __restrict__ qbuf,
    const int* __restrict__ obs, float* __restrict__ out_y) {
  __shared__ __align__(16) float cc[64 * 100];
  __shared__ __align__(16) float uc[64 * 100];
  __shared__ __align__(16) float wc[64 * 2];
  __shared__ __align__(16) float hc[64 * 8];
  __shared__ float W1l[800];
  __shared__ float b1l[8];
  __shared__ int obsl[12];
  const int tid = threadIdx.x;
  const int blk = blockIdx.x;
  const int base = blk * 256;
  const int row = tid >> 1, half = tid & 1;
  float aW[52];
  float w2h0 = 0.f, w2h1 = 0.f, w2h2 = 0.f, w2h3 = 0.f;
  float bw0 = 0.f, bw1 = 0.f, cst = 0.f;
  if (tid < 200) {
    #pragma unroll
    for (int j = 0; j < 52; ++j) {
      int col = half * 48 + j;
      bool valid = half ? (j >= 2) : (j < 50);
      aW[j] = valid ? Amat[row * SD + col] : 0.f;
    }
    if (MODE >= 2) {
      w2h0 = W2[row * 8 + half * 4 + 0];
      w2h1 = W2[row * 8 + half * 4 + 1];
      w2h2 = W2[row * 8 + half * 4 + 2];
      w2h3 = W2[row * 8 + half * 4 + 3];
    } else if (half == 0) {
      bw0 = Bw[row * 2 + 0];
      bw1 = Bw[row * 2 + 1];
      cst = DT_F * b2v[row];
    }
  }
  if (MODE == 1) {
    for (int i = tid; i < 800; i += 256) W1l[i] = W1[i];
    if (tid < 8) b1l[tid] = b1v[tid];
  }
  if (MODE == 3 && tid < 12) obsl[tid] = obs[tid];
  if (tid < SD) {
    float v = 0.f;
    if (MODE == 1 || MODE == 3) v = Xin[blk * SD + tid];
    cc[63 * SD + tid] = v;
  }
  if (MODE == 1 && blk == 0 && tid < 8) {
    float q0 = b1v[tid];
    for (int l = 0; l < SD; ++l) q0 = fmaf(W1[tid * SD + l], c0[l], q0);
    qbuf[tid] = q0;
  }

  for (int kk = 0; kk < 4; ++kk) {
    __syncthreads();
    if (MODE < 2) {
      const float* us = ug + (size_t)(base + kk * 64) * SD;
      for (int i = tid; i < 1600; i += 256) ((float4*)uc)[i] = ((const float4*)us)[i];
      if (tid < 128) wc[tid] = wg[(size_t)(base + kk * 64) * 2 + tid];
    } else {
      const float* hs = hbufg + (size_t)(base + kk * 64) * 8;
      for (int i = tid; i < 128; i += 256) ((float4*)hc)[i] = ((const float4*)hs)[i];
    }
    for (int t = 0; t < 64; ++t) {
      __syncthreads();
      const float* cprev = cc + ((t + 63) & 63) * SD;
      if (tid < 200) {
        const float4* cb = (const float4*)cprev + half * 12;
        float p0 = 0.f, p1 = 0.f, p2 = 0.f, p3 = 0.f;
        #pragma unroll
        for (int i = 0; i < 13; ++i) {
          float4 c4 = cb[i];
          p0 = fmaf(aW[4 * i + 0], c4.x, p0);
          p1 = fmaf(aW[4 * i + 1], c4.y, p1);
          p2 = fmaf(aW[4 * i + 2], c4.z, p2);
          p3 = fmaf(aW[4 * i + 3], c4.w, p3);
        }
        float acc = (p0 + p1) + (p2 + p3);
        if (MODE >= 2) {
          float4 h4 = *(const float4*)(hc + t * 8 + half * 4);
          acc = fmaf(w2h0, h4.x, acc);
          acc = fmaf(w2h1, h4.y, acc);
          acc = fmaf(w2h2, h4.z, acc);
          acc = fmaf(w2h3, h4.w, acc);
        } else if (half == 0) {
          float2 wv = *(const float2*)(wc + t * 2);
          acc += cst + bw0 * wv.x + bw1 * wv.y + uc[t * SD + row];
        }
        acc = dpp_xor1_add(acc);
        if (half == 0) cc[t * SD + row] = acc;
      }
    }
    __syncthreads();
    if (MODE == 1) {
      float4* Ld = (float4*)(Lc + (size_t)(base + kk * 64) * SD);
      for (int i = tid; i < 1600; i += 256) Ld[i] = ((const float4*)cc)[i];
      for (int e = tid; e < 512; e += 256) {
        int sl = e >> 3, zr = e & 7;
        float qv = b1l[zr];
        const float4* crow = (const float4*)(cc + sl * SD);
        const float* wr = W1l + zr * SD;
        #pragma unroll
        for (int i = 0; i < 25; ++i) {
          float4 c4 = crow[i];
          qv = fmaf(wr[4 * i + 0], c4.x, qv);
          qv = fmaf(wr[4 * i + 1], c4.y, qv);
          qv = fmaf(wr[4 * i + 2], c4.z, qv);
          qv = fmaf(wr[4 * i + 3], c4.w, qv);
        }
        qbuf[(size_t)(base + kk * 64 + sl + 1) * 8 + zr] = qv;
      }
    } else if (MODE == 3) {
      for (int e = tid; e < 768; e += 256) {
        int sl = e / 12, j = e - sl * 12;
        int tg = base + kk * 64 + sl;
        out_y[(size_t)tg * 12 + j] =
            Lc[(size_t)tg * SD + obsl[j]] + DT_F * cc[sl * SD + obsl[j]];
      }
      __syncthreads();
      float4* Ld = (float4*)(Lc + (size_t)(base + kk * 64) * SD);
      for (int i = tid; i < 1600; i += 256) {
        float4 L4 = Ld[i];
        float4 r4 = ((const float4*)cc)[i];
        L4.x = fmaf(DT_F, r4.x, L4.x);
        L4.y = fmaf(DT_F, r4.y, L4.y);
        L4.z = fmaf(DT_F, r4.z, L4.z);
        L4.w = fmaf(DT_F, r4.w, L4.w);
        Ld[i] = L4;
      }
    }
  }
  if (MODE == 0 || MODE == 2) {
    __syncthreads();
    if (tid < 25)
      ((float4*)(SendOut + blk * SD))[tid] = ((const float4*)(cc + 63 * SD))[tid];
  }
}

// ---------- scan: X[b+1] = A256 X[b] + Send[b] ----------
__global__ __launch_bounds__(256, 1) void k_scan(
    const float* __restrict__ A256, const float* __restrict__ Send,
    const float* __restrict__ c0, int use_c0, float* __restrict__ Xout) {
  __shared__ __align__(16) float X[256][100];
  __shared__ __align__(16) float sc[64 * 100];
  const int tid = threadIdx.x;
  const int row = tid >> 1, half = tid & 1;
  float aW[52];
  if (tid < 200) {
    #pragma unroll
    for (int j = 0; j < 52; ++j) {
      int col = half * 48 + j;
      bool valid = half ? (j >= 2) : (j < 50);
      aW[j] = valid ? A256[row * SD + col] : 0.f;
    }
  }
  if (tid < SD) X[0][tid] = use_c0 ? c0[tid] : 0.f;
  for (int b = 0; b < 255; ++b) {
    if ((b & 63) == 0) {
      __syncthreads();
      for (int i = tid; i < 1600; i += 256)
        ((float4*)sc)[i] = ((const float4*)(Send + b * SD))[i];
    }
    __syncthreads();
    if (tid < 200) {
      const float4* cb = (const float4*)(&X[b][0]) + half * 12;
      float p0 = 0.f, p1 = 0.f, p2 = 0.f, p3 = 0.f;
      #pragma unroll
      for (int i = 0; i < 13; ++i) {
        float4 c4 = cb[i];
        p0 = fmaf(aW[4 * i + 0], c4.x, p0);
        p1 = fmaf(aW[4 * i + 1], c4.y, p1);
        p2 = fmaf(aW[4 * i + 2], c4.z, p2);
        p3 = fmaf(aW[4 * i + 3], c4.w, p3);
      }
      float acc = (p0 + p1) + (p2 + p3);
      if (half == 0) acc += sc[(b & 63) * SD + row];
      acc = dpp_xor1_add(acc);
      if (half == 0) X[b + 1][row] = acc;
    }
  }
  __syncthreads();
  for (int i = tid; i < 6400; i += 256) ((float4*)Xout)[i] = ((const float4*)X)[i];
}

// ---------- K4: sequential core ----------
// zb2[slot][comp][2]: word 0 = conv-chain partial (wave-0 conv lanes),
// word 1 = base (wave 2). Quad reads the pair with ONE ds_read_b64 when the
// slot's base is stable (TT=0..5); split reads for TT=6,7 (next-block base
// is being written this iteration; its read stays post-barrier).
#define QSTEP(BASE, TT)                                                       \
  {                                                                           \
    const int SL = (BASE) + (TT);                                             \
    float sB = 0.f, seedC = 0.f;                                              \
    if (lane >= 8) {                                                          \
      const float* hp = hs[((TT) + 1) & 1];                                   \
      sB = GcB[0] * hp[0];                                                    \
      sB = fmaf(GcB[1], hp[1], sB); sB = fmaf(GcB[2], hp[2], sB);             \
      sB = fmaf(GcB[3], hp[3], sB); sB = fmaf(GcB[4], hp[4], sB);             \
      sB = fmaf(GcB[5], hp[5], sB); sB = fmaf(GcB[6], hp[6], sB);             \
      sB = fmaf(GcB[7], hp[7], sB);                                           \
      seedC = chainpre + s2s[((TT) + 2) & 7];                                 \
    }                                                                         \
    if (lane < 16) {                                                          \
      float hg1 = dppq<0xB1>(cur);                                            \
      float hg2 = dppq<0x4E>(cur);                                            \
      float hg3 = dppq<0x1B>(cur);                                            \
      float vx4 = dppq<0x124>(cur);                                           \
      float za = fmaf(G0p[0], cur, chainP[(TT) & 1]);                         \
      za = fmaf(G0p[1], hg1, za);                                             \
      za = fmaf(G0p[2], hg2, za);                                             \
      za = fmaf(G0p[3], hg3, za);                                             \
      float zc = fmaf(G0p[4], vx4, baseP[(TT) & 1]);                          \
      zc = fmaf(G0p[5], dppq<0xB1>(vx4), zc);                                 \
      zc = fmaf(G0p[6], dppq<0x4E>(vx4), zc);                                 \
      zc = fmaf(G0p[7], dppq<0x1B>(vx4), zc);                                 \
      cur = tanh_fast(za + zc);                                               \
      hring[SL * 8 + l7] = cur;                                               \
    }                                                                         \
    {                                                                         \
      float* hn = hs[(TT) & 1];                                               \
      hn[0] = rdlane(cur, 0); hn[1] = rdlane(cur, 1);                         \
      hn[2] = rdlane(cur, 2); hn[3] = rdlane(cur, 3);                         \
      hn[4] = rdlane(cur, 4); hn[5] = rdlane(cur, 5);                         \
      hn[6] = rdlane(cur, 6); hn[7] = rdlane(cur, 7);                         \
      if (lane >= 8) {                                                        \
        float acc = fmaf(GcA[0], hn[0], seedC);                               \
        acc = fmaf(GcA[1], hn[1], acc); acc = fmaf(GcA[2], hn[2], acc);       \
        acc = fmaf(GcA[3], hn[3], acc); acc = fmaf(GcA[4], hn[4], acc);       \
        acc = fmaf(GcA[5], hn[5], acc); acc = fmaf(GcA[6], hn[6], acc);       \
        acc = fmaf(GcA[7], hn[7], acc);                                       \
        s2s[(TT) & 7] = sB;                                                   \
        *(float*)((char*)zb2 + addrW[SL]) = acc;                              \
        chainpre = *(const float*)((char*)zb2 + addrR[SL]);                   \
      }                                                                       \
    }                                                                         \
    if (lane < 16) {                                                          \
      if ((TT) < 6) {                                                         \
        float2 pr = *(const float2*)&zb2[((SL + 2) & 15) * 16 + l7 * 2];      \
        chainP[(TT) & 1] = pr.x;                                              \
        baseP[(TT) & 1] = pr.y;                                               \
      } else {                                                                \
        chainP[(TT) & 1] = zb2[((SL + 2) & 15) * 16 + l7 * 2];                \
      }                                                                       \
    }                                                                         \
  }

#define K4_HALF(BASE, DOFLUSH)                                                \
  {                                                                           \
    if (lane < 16) {                                                          \
      baseP[0] = zb2[(BASE) * 16 + l7 * 2 + 1];                               \
      baseP[1] = zb2[((BASE) + 1) * 16 + l7 * 2 + 1];                         \
    }                                                                         \
    if (DOFLUSH) {                                                            \
      if (lane < 4) {                                                         \
        const float* fsrc = hring + ((BASE) ? 0 : 64) + lane * 16;            \
        float4* fdst = (float4*)(hflush + lane * 16);                         \
        fdst[0] = *(const float4*)(fsrc);                                     \
        fdst[1] = *(const float4*)(fsrc + 4);                                 \
        fdst[2] = *(const float4*)(fsrc + 8);                                 \
        fdst[3] = *(const float4*)(fsrc + 12);                                \
      }                                                                       \
      hflush += 64;                                                           \
    }                                                                         \
    QSTEP(BASE, 0) QSTEP(BASE, 1) QSTEP(BASE, 2) QSTEP(BASE, 3)               \
    QSTEP(BASE, 4) QSTEP(BASE, 5) QSTEP(BASE, 6) QSTEP(BASE, 7)               \
    __syncthreads();                                                          \
  }

__global__ __launch_bounds__(256, 1) void k4_core(
    const float* __restrict__ qbuf, const float* __restrict__ A8w,
    const float* __restrict__ Pws, const float* __restrict__ Gws,
    const float* __restrict__ Qws, float* __restrict__ hbuf,
    unsigned int* flagp) {
  const int tid = threadIdx.x;
  // 80KB guard: forces 1 block/CU so fillers never share block-0's CU.
  __shared__ float lds_guard[20480];
  if (flagp == (unsigned int*)0) lds_guard[tid] = 1.f;  // never true; keeps alloc

  // ---- DVFS-hold fillers: 4 dense waves, 8 indep FMA chains, poll/64 ----
  if (blockIdx.x != 0) {
    float x0 = 1.f, x1 = 1.01f, x2 = 1.02f, x3 = 1.03f;
    float x4 = 1.04f, x5 = 1.05f, x6 = 1.06f, x7 = 1.07f;
    for (int it = 0; it < 600000; ++it) {
      #pragma unroll
      for (int j = 0; j < 4; ++j) {
        x0 = fmaf(x0, 1.0000001f, 1e-30f);
        x1 = fmaf(x1, 0.9999999f, 1e-30f);
        x2 = fmaf(x2, 1.0000002f, 1e-30f);
        x3 = fmaf(x3, 0.9999998f, 1e-30f);
        x4 = fmaf(x4, 1.0000003f, 1e-30f);
        x5 = fmaf(x5, 0.9999997f, 1e-30f);
        x6 = fmaf(x6, 1.0000004f, 1e-30f);
        x7 = fmaf(x7, 0.9999996f, 1e-30f);
      }
      if ((it & 63) == 0) {
        if (__hip_atomic_load(flagp, __ATOMIC_RELAXED,
                              __HIP_MEMORY_SCOPE_AGENT) != 0u)
          break;
      }
    }
    asm volatile("" ::"v"(x0), "v"(x1), "v"(x2), "v"(x3), "v"(x4), "v"(x5),
                 "v"(x6), "v"(x7));
    return;
  }

  __shared__ __align__(16) float zb2[16 * 16 + 8];  // fused plane + dummy0
  __shared__ __align__(16) float hring[16 * 8];
  __shared__ __align__(16) float rbuf[2][100];
  const int wave = tid >> 6;
  const int lane = tid & 63;

  // zero chain words (even) + dummy; base words (odd) are wave-2-owned.
  for (int i = tid; i < 128; i += 256) zb2[2 * i] = 0.f;
  if (tid < 8) zb2[256 + tid] = 0.f;
  for (int i = tid; i < 128; i += 256) hring[i] = 0.f;
  if (tid < 200) ((float*)rbuf)[tid] = 0.f;

  if (wave == 0) {
    __builtin_amdgcn_s_setprio(1);
    const int l7 = lane & 7;
    const int g = (lane >> 3) - 1;  // conv group 0..6 for lanes 8..63
    const int ci = lane & 7;
    float G0p[8];
    float GcA[8], GcB[8];
    int addrW[16], addrR[16];
    if (lane < 16) {
      #pragma unroll
      for (int o = 0; o < 8; ++o) G0p[o] = Gws[l7 * 8 + (l7 ^ o)];
    }
    if (lane >= 8) {
      const int kA = 1 + g;  // taps 1..7
      const int kB = 8 + g;  // taps 8..14 (6-step reg pipe + 1-step-late calc)
      #pragma unroll
      for (int c = 0; c < 8; ++c) {
        GcA[c] = Gws[kA * 64 + ci * 8 + c];
        GcB[c] = Gws[kB * 64 + ci * 8 + c];
      }
      #pragma unroll
      for (int k = 0; k < 16; ++k)
        addrW[k] = (((k + 2 + g) & 15) * 16 + ci * 2) * 4;
      #pragma unroll
      for (int k = 0; k < 16; ++k)
        addrR[k] = (g == 6) ? (256 + ci) * 4 : addrW[(k + 1) & 15];
    }
    __syncthreads();  // matches other waves' init barrier

    float cur = 0.f, chainpre = 0.f;
    float chainP[2], baseP[2];
    float s2s[8];
    float hs[2][8];
    chainP[0] = 0.f;  // zb2 chain slots 0,1 (zeroed)
    chainP[1] = 0.f;
    baseP[0] = 0.f;
    baseP[1] = 0.f;
    #pragma unroll
    for (int j = 0; j < 8; ++j) { s2s[j] = 0.f; hs[0][j] = 0.f; hs[1][j] = 0.f; }
    float* hflush = hbuf;

    K4_HALF(0, 0)
    K4_HALF(8, 1)
    for (int mm = 1; mm < 4096; ++mm) {
      K4_HALF(0, 1)
      K4_HALF(8, 1)
    }
    if (lane < 4) {  // flush h of final block (8191, ring half 1)
      const float* fsrc = hring + 64 + lane * 16;
      float4* fdst = (float4*)(hflush + lane * 16);
      fdst[0] = *(const float4*)(fsrc);
      fdst[1] = *(const float4*)(fsrc + 4);
      fdst[2] = *(const float4*)(fsrc + 8);
      fdst[3] = *(const float4*)(fsrc + 12);
    }
  } else if (wave == 1 || wave == 3) {
    // ---- r-advance: r_m = A^8 r_{m-1} + sum_i Q_i h[(m-1)*8+i] ----
    // LDS-lean: scatter loads + v_readlane broadcasts (literal lanes).
    const int rrow = (wave == 1) ? lane : 64 + lane;
    float A8row[100];
    float Qrow[64];
    if (rrow < 100) {
      #pragma unroll
      for (int i = 0; i < 25; ++i)
        *(float4*)&A8row[4 * i] = ((const float4*)(A8w + rrow * 100))[i];
      #pragma unroll
      for (int i = 0; i < 8; ++i)
        #pragma unroll
        for (int c = 0; c < 8; ++c) Qrow[i * 8 + c] = Qws[i * 800 + rrow * 8 + c];
    }
    const int hi_idx = 64 + (lane < 36 ? lane : 35);
    __syncthreads();
    for (int m = 0; m < 8192; ++m) {
      const int prev = (m + 1) & 1;
      float r_lo = rbuf[prev][lane];
      float r_hi = rbuf[prev][hi_idx];
      float h_my = hring[((m - 1) & 1) * 64 + lane];
      float p[4] = {0.f, 0.f, 0.f, 0.f};
      #pragma unroll
      for (int c = 0; c < 100; ++c) {
        float s = (c < 64) ? rdlane(r_lo, c) : rdlane(r_hi, c - 64);
        p[c & 3] = fmaf(A8row[c], s, p[c & 3]);
      }
      float q[4] = {0.f, 0.f, 0.f, 0.f};
      #pragma unroll
      for (int j = 0; j < 64; ++j) {
        float s = rdlane(h_my, j);
        q[j & 3] = fmaf(Qrow[j], s, q[j & 3]);
      }
      if (rrow < 100)
        rbuf[m & 1][rrow] =
            ((p[0] + p[1]) + (p[2] + p[3])) + ((q[0] + q[1]) + (q[2] + q[3]));
      __syncthreads();
    }
  } else {
    // ---- wave 2: base plane (odd words of zb2) for block m+1 ----
    const int wj = lane >> 3, wi = lane & 7;
    float Prow[100];
    float Gw2[64];
    #pragma unroll
    for (int i = 0; i < 25; ++i)
      *(float4*)&Prow[4 * i] = ((const float4*)(Pws + wj * 800 + wi * 100))[i];
    #pragma unroll
    for (int jj = 0; jj < 8; ++jj)
      #pragma unroll
      for (int c = 0; c < 8; ++c)
        Gw2[jj * 8 + c] =
            (jj > wj) ? 0.f : Gws[(15 + wj - jj) * 64 + wi * 8 + c];
    float qpipe[4];
    #pragma unroll
    for (int i = 0; i < 4; ++i)
      qpipe[i] = qbuf[(size_t)((i + 1) * 8 + wj) * 8 + wi];
    zb2[wj * 16 + wi * 2 + 1] = qbuf[wj * 8 + wi];  // block-0 base = q
    const int hi_idx = 64 + (lane < 36 ? lane : 35);
    __syncthreads();
    for (int mo = 0; mo < 2048; ++mo) {
      #pragma unroll
      for (int mi = 0; mi < 4; ++mi) {
        const int m = mo * 4 + mi;
        float qv = qpipe[mi];
        int mp = m + 5;
        if (mp > 8192) mp = 8192;
        qpipe[mi] = qbuf[(size_t)(mp * 8 + wj) * 8 + wi];
        const int prev = (mi + 1) & 1;
        float r_lo = rbuf[prev][lane];
        float r_hi = rbuf[prev][hi_idx];
        float h_my = hring[((mi + 1) & 1) * 64 + lane];
        float p[4] = {0.f, 0.f, 0.f, 0.f};
        #pragma unroll
        for (int c = 0; c < 100; ++c) {
          float s = (c < 64) ? rdlane(r_lo, c) : rdlane(r_hi, c - 64);
          p[c & 3] = fmaf(Prow[c], s, p[c & 3]);
        }
        float gg[4] = {0.f, 0.f, 0.f, 0.f};
        #pragma unroll
        for (int j = 0; j < 64; ++j) {
          float s = rdlane(h_my, j);
          gg[j & 3] = fmaf(Gw2[j], s, gg[j & 3]);
        }
        zb2[((((mi + 1) & 1) * 8 + wj)) * 16 + wi * 2 + 1] =
            qv + ((p[0] + p[1]) + (p[2] + p[3])) +
            ((gg[0] + gg[1]) + (gg[2] + gg[3]));
        __syncthreads();
      }
    }
  }

  // ---- all of block 0 done: release the fillers ----
  __syncthreads();
  if (tid == 0)
    __hip_atomic_store(flagp, 1u, __ATOMIC_RELAXED, __HIP_MEMORY_SCOPE_AGENT);
}

// ---------- launch ----------
extern "C" void kernel_launch(void* const* d_in, const int* in_sizes, int n_in,
                              void* d_out, int out_size, void* d_ws, size_t ws_size,
                              hipStream_t stream) {
  const float* c0 = (const float*)d_in[0];
  const float* w  = (const float*)d_in[1];
  const float* u  = (const float*)d_in[2];
  const float* A  = (const float*)d_in[3];
  const float* Bw = (const float*)d_in[4];
  const float* W1 = (const float*)d_in[5];
  const float* b1 = (const float*)d_in[6];
  const float* W2 = (const float*)d_in[7];
  const float* b2 = (const float*)d_in[8];
  const int* obs  = (const int*)d_in[9];
  float* out_c = (float*)d_out;
  float* out_y = out_c + (size_t)T_STEPS * SD;

  float* wsf = (float*)d_ws;
  float* A8    = wsf;                 // 10000
  float* A256  = wsf + 10000;         // 10000
  float* Pws   = wsf + 20000;         // 8*800
  float* Gws   = wsf + 26400;         // 23*64
  float* Qws   = wsf + 27872;         // 8*800
  float* Send  = wsf + 34272;         // 256*100 (dead after k_scan -> flag)
  float* X     = wsf + 59872;         // 256*100
  float* qbuf  = wsf + 85472;         // (T+16)*8
  float* hbuf  = wsf + 609888;        // T*8 + 64
  float* SendR = wsf + 1134240;       // 256*100
  float* XR    = wsf + 1159840;       // 256*100

  hipLaunchKernelGGL(k0_setup, dim3(1), dim3(256), 0, stream,
                     A, W1, W2, A8, A256, Pws, Gws, Qws);
  hipLaunchKernelGGL(k_rollout<0>, dim3(256), dim3(256), 0, stream,
                     A, Bw, b2, u, w, (const float*)nullptr, (const float*)nullptr,
                     (const float*)nullptr, (const float*)nullptr, (const float*)nullptr,
                     (const float*)nullptr, Send, (float*)nullptr, (float*)nullptr,
                     (const int*)nullptr, (float*)nullptr);
  hipLaunchKernelGGL(k_scan, dim3(1), dim3(256), 0, stream, A256, Send, c0, 1, X);
  hipLaunchKernelGGL(k_rollout<1>, dim3(256), dim3(256), 0, stream,
                     A, Bw, b2, u, w, (const float*)nullptr, (const float*)nullptr,
                     W1, b1, c0, X, (float*)nullptr, out_c, qbuf,
                     (const int*)nullptr, (float*)nullptr);
  // Send is dead now (consumed by k_scan). Reuse its first word as the
  // filler release flag for k4_core.
  hipMemsetAsync(Send, 0, sizeof(unsigned int), stream);
  hipLaunchKernelGGL(k4_core, dim3(256), dim3(256), 0, stream,
                     qbuf, A8, Pws, Gws, Qws, hbuf, (unsigned int*)Send);
  hipLaunchKernelGGL(k_rollout<2>, dim3(256), dim3(256), 0, stream,
                     A, (const float*)nullptr, (const float*)nullptr,
                     (const float*)nullptr, (const float*)nullptr, W2, hbuf,
                     (const float*)nullptr, (const float*)nullptr, (const float*)nullptr,
                     (const float*)nullptr, SendR, (float*)nullptr, (float*)nullptr,
                     (const int*)nullptr, (float*)nullptr);
  hipLaunchKernelGGL(k_scan, dim3(1), dim3(256), 0, stream, A256, SendR,
                     (const float*)nullptr, 0, XR);
  hipLaunchKernelGGL(k_rollout<3>, dim3(256), dim3(256), 0, stream,
                     A, (const float*)nullptr, (const float*)nullptr,
                     (const float*)nullptr, (const float*)nullptr, W2, hbuf,
                     (const float*)nullptr, (const float*)nullptr, (const float*)nullptr,
                     XR, (float*)nullptr, out_c, (float*)nullptr, obs, out_y);
}

// Round 10
// 12691.283 us; speedup vs baseline: 1.0267x; 1.0267x over previous
//
#include <hip/hip_runtime.h>
#include <math.h>

// GreyBox rollout, FINAL (revert to round 10 — session best: 12.73 ms total,
// k4 ~11.8 ms). Round 11's fused-plane variant regressed (+1.9%, bank
// conflicts 49K->311K) and fell inside the pre-committed <3% plateau band.
// Conclusion: k4's ~450 nominal-cyc/step floor is structural — the serial
// tanh->DPP->FMA recurrence + ~48-instr issue + barrier rendezvous on one
// pace wave, with T=65536 strictly sequential steps. All other theories
// (DVFS floor, LDS latency, LDS-pipe contention, scheduling) were
// experimentally refuted in rounds 7-10.

#define T_STEPS 65536
#define SD 100
#define DT_F 0.01f

// ---------- helpers ----------
__device__ __forceinline__ float dpp_xor1_add(float x) {
  int v = __builtin_amdgcn_update_dpp(0, __float_as_int(x), 0xB1, 0xF, 0xF, true);
  return x + __int_as_float(v);
}
template <int PAT>
__device__ __forceinline__ float dppq(float x) {
  return __int_as_float(__builtin_amdgcn_update_dpp(0, __float_as_int(x), PAT, 0xF, 0xF, true));
}
__device__ __forceinline__ float tanh_fast(float x) {
  // tanh(x) = 1 - 2/(e^{2x}+1);  e^{2x} = exp2(x * 2/ln2)
  float e = __builtin_amdgcn_exp2f(x * 2.885390081777927f);
  return 1.f - 2.f * __builtin_amdgcn_rcpf(e + 1.f);
}
__device__ __forceinline__ float rdlane(float v, int l) {
  return __int_as_float(__builtin_amdgcn_readlane(__float_as_int(v), l));
}

// ---------- K0: setup (A^8, A^256, P_k=DT*W1A^k (k=16..23), G_k=DT*W1A^kW2
// (k=0..22), Q_i=A^{7-i}W2) ----------
__global__ __launch_bounds__(256, 1) void k0_setup(
    const float* __restrict__ A, const float* __restrict__ W1,
    const float* __restrict__ W2, float* __restrict__ A8o,
    float* __restrict__ A256o, float* __restrict__ Pws,
    float* __restrict__ Gws, float* __restrict__ Qws) {
  __shared__ __align__(16) float Al[10000];
  __shared__ __align__(16) float M0[10000];
  __shared__ __align__(16) float M1[10000];
  __shared__ __align__(16) float Pb[2][800];
  __shared__ __align__(16) float Vb[2][800];
  const int tid = threadIdx.x;
  for (int i = tid; i < 2500; i += 256) {
    ((float4*)Al)[i] = ((const float4*)A)[i];
    ((float4*)M0)[i] = ((const float4*)A)[i];
  }
  __syncthreads();
  // squarings: after s, result in ((s&1)?M0:M1). s=2 -> A^8, s=7 -> A^256.
  for (int s = 0; s < 8; ++s) {
    const float* src = (s & 1) ? M1 : M0;
    float* dst = (s & 1) ? M0 : M1;
    if (tid < 100) {
      float4 acc[25];
      #pragma unroll
      for (int i = 0; i < 25; ++i) acc[i] = make_float4(0.f, 0.f, 0.f, 0.f);
      for (int k = 0; k < 100; ++k) {
        float a = src[tid * 100 + k];
        const float4* rk = (const float4*)(src + k * 100);
        #pragma unroll
        for (int i = 0; i < 25; ++i) {
          float4 r4 = rk[i];
          acc[i].x = fmaf(a, r4.x, acc[i].x);
          acc[i].y = fmaf(a, r4.y, acc[i].y);
          acc[i].z = fmaf(a, r4.z, acc[i].z);
          acc[i].w = fmaf(a, r4.w, acc[i].w);
        }
      }
      #pragma unroll
      for (int i = 0; i < 25; ++i) ((float4*)(dst + tid * 100))[i] = acc[i];
    }
    __syncthreads();
    if (s == 2) for (int i = tid; i < 2500; i += 256) ((float4*)A8o)[i] = ((const float4*)dst)[i];
    if (s == 7) for (int i = tid; i < 2500; i += 256) ((float4*)A256o)[i] = ((const float4*)dst)[i];
    __syncthreads();
  }
  // P chain: P_0 = W1; P_k = P_{k-1} A. Store G_k (k<=22), P_k (16<=k<=23).
  for (int i = tid; i < 800; i += 256) Pb[0][i] = W1[i];
  __syncthreads();
  for (int k = 0; k < 24; ++k) {
    const float* Pc = Pb[k & 1];
    if (k <= 22 && tid < 64) {
      int i = tid >> 3, c = tid & 7;
      float g = 0.f;
      for (int l = 0; l < 100; ++l) g = fmaf(Pc[i * 100 + l], W2[l * 8 + c], g);
      Gws[k * 64 + i * 8 + c] = DT_F * g;
    }
    if (k >= 16) for (int i = tid; i < 800; i += 256) Pws[(k - 16) * 800 + i] = DT_F * Pc[i];
    __syncthreads();
    if (k < 23) {
      float* Pn = Pb[(k + 1) & 1];
      if (tid < 64) {
        int i = tid >> 3, cg = tid & 7;
        int c0 = cg * 13, c1 = c0 + 13 < 100 ? c0 + 13 : 100;
        for (int c = c0; c < c1; ++c) {
          float v = 0.f;
          for (int l = 0; l < 100; ++l) v = fmaf(Pc[i * 100 + l], Al[l * 100 + c], v);
          Pn[i * 100 + c] = v;
        }
      }
    }
    __syncthreads();
  }
  // V chain: V_0 = W2; V_j = A V_{j-1}. Q_i = V_{7-i} (unscaled).
  for (int i = tid; i < 800; i += 256) Vb[0][i] = W2[i];
  __syncthreads();
  for (int j = 0; j < 8; ++j) {
    const float* Vc = Vb[j & 1];
    for (int i = tid; i < 800; i += 256) Qws[(7 - j) * 800 + i] = Vc[i];
    __syncthreads();
    if (j < 7 && tid < 100) {
      float acc[8];
      #pragma unroll
      for (int c = 0; c < 8; ++c) acc[c] = 0.f;
      for (int l = 0; l < 100; ++l) {
        float av = Al[tid * 100 + l];
        #pragma unroll
        for (int c = 0; c < 8; ++c) acc[c] = fmaf(av, Vc[l * 8 + c], acc[c]);
      }
      float* dst = Vb[(j + 1) & 1] + tid * 8;
      #pragma unroll
      for (int c = 0; c < 8; ++c) dst[c] = acc[c];
    }
    __syncthreads();
  }
}

// ---------- rollout kernel (4 modes) ----------
// MODE 0: LIN local  (init 0, d = Bw w + u + DT b2)      -> SendOut
// MODE 1: LIN fix    (init X[b])                          -> out L, qbuf
// MODE 2: RHO local  (init 0, d = W2 h)                   -> SendOut
// MODE 3: RHO fix    (init XR[b])                         -> c = L+DT*rho, y
template <int MODE>
__global__ __launch_bounds__(256, 1) void k_rollout(
    const float* __restrict__ Amat, const float* __restrict__ Bw,
    const float* __restrict__ b2v, const float* __restrict__ ug,
    const float* __restrict__ wg, const float* __restrict__ W2,
    const float* __restrict__ hbufg, const float* __restrict__ W1,
    const float* __restrict__ b1v, const float* __restrict__ c0,
    const float* __restrict__ Xin, float* __restrict__ SendOut,
    float* __restrict__ Lc, float* __restrict__ qbuf,
    const int* __restrict__ obs, float* __restrict__ out_y) {
  __shared__ __align__(16) float cc[64 * 100];
  __shared__ __align__(16) float uc[64 * 100];
  __shared__ __align__(16) float wc[64 * 2];
  __shared__ __align__(16) float hc[64 * 8];
  __shared__ float W1l[800];
  __shared__ float b1l[8];
  __shared__ int obsl[12];
  const int tid = threadIdx.x;
  const int blk = blockIdx.x;
  const int base = blk * 256;
  const int row = tid >> 1, half = tid & 1;
  float aW[52];
  float w2h0 = 0.f, w2h1 = 0.f, w2h2 = 0.f, w2h3 = 0.f;
  float bw0 = 0.f, bw1 = 0.f, cst = 0.f;
  if (tid < 200) {
    #pragma unroll
    for (int j = 0; j < 52; ++j) {
      int col = half * 48 + j;
      bool valid = half ? (j >= 2) : (j < 50);
      aW[j] = valid ? Amat[row * SD + col] : 0.f;
    }
    if (MODE >= 2) {
      w2h0 = W2[row * 8 + half * 4 + 0];
      w2h1 = W2[row * 8 + half * 4 + 1];
      w2h2 = W2[row * 8 + half * 4 + 2];
      w2h3 = W2[row * 8 + half * 4 + 3];
    } else if (half == 0) {
      bw0 = Bw[row * 2 + 0];
      bw1 = Bw[row * 2 + 1];
      cst = DT_F * b2v[row];
    }
  }
  if (MODE == 1) {
    for (int i = tid; i < 800; i += 256) W1l[i] = W1[i];
    if (tid < 8) b1l[tid] = b1v[tid];
  }
  if (MODE == 3 && tid < 12) obsl[tid] = obs[tid];
  if (tid < SD) {
    float v = 0.f;
    if (MODE == 1 || MODE == 3) v = Xin[blk * SD + tid];
    cc[63 * SD + tid] = v;
  }
  if (MODE == 1 && blk == 0 && tid < 8) {
    float q0 = b1v[tid];
    for (int l = 0; l < SD; ++l) q0 = fmaf(W1[tid * SD + l], c0[l], q0);
    qbuf[tid] = q0;
  }

  for (int kk = 0; kk < 4; ++kk) {
    __syncthreads();
    if (MODE < 2) {
      const float* us = ug + (size_t)(base + kk * 64) * SD;
      for (int i = tid; i < 1600; i += 256) ((float4*)uc)[i] = ((const float4*)us)[i];
      if (tid < 128) wc[tid] = wg[(size_t)(base + kk * 64) * 2 + tid];
    } else {
      const float* hs = hbufg + (size_t)(base + kk * 64) * 8;
      for (int i = tid; i < 128; i += 256) ((float4*)hc)[i] = ((const float4*)hs)[i];
    }
    for (int t = 0; t < 64; ++t) {
      __syncthreads();
      const float* cprev = cc + ((t + 63) & 63) * SD;
      if (tid < 200) {
        const float4* cb = (const float4*)cprev + half * 12;
        float p0 = 0.f, p1 = 0.f, p2 = 0.f, p3 = 0.f;
        #pragma unroll
        for (int i = 0; i < 13; ++i) {
          float4 c4 = cb[i];
          p0 = fmaf(aW[4 * i + 0], c4.x, p0);
          p1 = fmaf(aW[4 * i + 1], c4.y, p1);
          p2 = fmaf(aW[4 * i + 2], c4.z, p2);
          p3 = fmaf(aW[4 * i + 3], c4.w, p3);
        }
        float acc = (p0 + p1) + (p2 + p3);
        if (MODE >= 2) {
          float4 h4 = *(const float4*)(hc + t * 8 + half * 4);
          acc = fmaf(w2h0, h4.x, acc);
          acc = fmaf(w2h1, h4.y, acc);
          acc = fmaf(w2h2, h4.z, acc);
          acc = fmaf(w2h3, h4.w, acc);
        } else if (half == 0) {
          float2 wv = *(const float2*)(wc + t * 2);
          acc += cst + bw0 * wv.x + bw1 * wv.y + uc[t * SD + row];
        }
        acc = dpp_xor1_add(acc);
        if (half == 0) cc[t * SD + row] = acc;
      }
    }
    __syncthreads();
    if (MODE == 1) {
      float4* Ld = (float4*)(Lc + (size_t)(base + kk * 64) * SD);
      for (int i = tid; i < 1600; i += 256) Ld[i] = ((const float4*)cc)[i];
      for (int e = tid; e < 512; e += 256) {
        int sl = e >> 3, zr = e & 7;
        float qv = b1l[zr];
        const float4* crow = (const float4*)(cc + sl * SD);
        const float* wr = W1l + zr * SD;
        #pragma unroll
        for (int i = 0; i < 25; ++i) {
          float4 c4 = crow[i];
          qv = fmaf(wr[4 * i + 0], c4.x, qv);
          qv = fmaf(wr[4 * i + 1], c4.y, qv);
          qv = fmaf(wr[4 * i + 2], c4.z, qv);
          qv = fmaf(wr[4 * i + 3], c4.w, qv);
        }
        qbuf[(size_t)(base + kk * 64 + sl + 1) * 8 + zr] = qv;
      }
    } else if (MODE == 3) {
      for (int e = tid; e < 768; e += 256) {
        int sl = e / 12, j = e - sl * 12;
        int tg = base + kk * 64 + sl;
        out_y[(size_t)tg * 12 + j] =
            Lc[(size_t)tg * SD + obsl[j]] + DT_F * cc[sl * SD + obsl[j]];
      }
      __syncthreads();
      float4* Ld = (float4*)(Lc + (size_t)(base + kk * 64) * SD);
      for (int i = tid; i < 1600; i += 256) {
        float4 L4 = Ld[i];
        float4 r4 = ((const float4*)cc)[i];
        L4.x = fmaf(DT_F, r4.x, L4.x);
        L4.y = fmaf(DT_F, r4.y, L4.y);
        L4.z = fmaf(DT_F, r4.z, L4.z);
        L4.w = fmaf(DT_F, r4.w, L4.w);
        Ld[i] = L4;
      }
    }
  }
  if (MODE == 0 || MODE == 2) {
    __syncthreads();
    if (tid < 25)
      ((float4*)(SendOut + blk * SD))[tid] = ((const float4*)(cc + 63 * SD))[tid];
  }
}

// ---------- scan: X[b+1] = A256 X[b] + Send[b] ----------
__global__ __launch_bounds__(256, 1) void k_scan(
    const float* __restrict__ A256, const float* __restrict__ Send,
    const float* __restrict__ c0, int use_c0, float* __restrict__ Xout) {
  __shared__ __align__(16) float X[256][100];
  __shared__ __align__(16) float sc[64 * 100];
  const int tid = threadIdx.x;
  const int row = tid >> 1, half = tid & 1;
  float aW[52];
  if (tid < 200) {
    #pragma unroll
    for (int j = 0; j < 52; ++j) {
      int col = half * 48 + j;
      bool valid = half ? (j >= 2) : (j < 50);
      aW[j] = valid ? A256[row * SD + col] : 0.f;
    }
  }
  if (tid < SD) X[0][tid] = use_c0 ? c0[tid] : 0.f;
  for (int b = 0; b < 255; ++b) {
    if ((b & 63) == 0) {
      __syncthreads();
      for (int i = tid; i < 1600; i += 256)
        ((float4*)sc)[i] = ((const float4*)(Send + b * SD))[i];
    }
    __syncthreads();
    if (tid < 200) {
      const float4* cb = (const float4*)(&X[b][0]) + half * 12;
      float p0 = 0.f, p1 = 0.f, p2 = 0.f, p3 = 0.f;
      #pragma unroll
      for (int i = 0; i < 13; ++i) {
        float4 c4 = cb[i];
        p0 = fmaf(aW[4 * i + 0], c4.x, p0);
        p1 = fmaf(aW[4 * i + 1], c4.y, p1);
        p2 = fmaf(aW[4 * i + 2], c4.z, p2);
        p3 = fmaf(aW[4 * i + 3], c4.w, p3);
      }
      float acc = (p0 + p1) + (p2 + p3);
      if (half == 0) acc += sc[(b & 63) * SD + row];
      acc = dpp_xor1_add(acc);
      if (half == 0) X[b + 1][row] = acc;
    }
  }
  __syncthreads();
  for (int i = tid; i < 6400; i += 256) ((float4*)Xout)[i] = ((const float4*)X)[i];
}

// ---------- K4: sequential core ----------
// Wave-0 per-step macro identical to round 9.
#define QSTEP(BASE, TT)                                                       \
  {                                                                           \
    const int SL = (BASE) + (TT);                                             \
    float sB = 0.f, seedC = 0.f;                                              \
    if (lane >= 8) {                                                          \
      const float* hp = hs[((TT) + 1) & 1];                                   \
      sB = GcB[0] * hp[0];                                                    \
      sB = fmaf(GcB[1], hp[1], sB); sB = fmaf(GcB[2], hp[2], sB);             \
      sB = fmaf(GcB[3], hp[3], sB); sB = fmaf(GcB[4], hp[4], sB);             \
      sB = fmaf(GcB[5], hp[5], sB); sB = fmaf(GcB[6], hp[6], sB);             \
      sB = fmaf(GcB[7], hp[7], sB);                                           \
      seedC = chainpre + s2s[((TT) + 2) & 7];                                 \
    }                                                                         \
    if (lane < 16) {                                                          \
      float zs = zbv[TT] + zpP[(TT) & 1];                                     \
      float za = fmaf(G0p[0], cur, zs);                                       \
      za = fmaf(G0p[1], dppq<0xB1>(cur), za);                                 \
      za = fmaf(G0p[2], dppq<0x4E>(cur), za);                                 \
      za = fmaf(G0p[3], dppq<0x1B>(cur), za);                                 \
      float vx4 = dppq<0x124>(cur);                                           \
      za = fmaf(G0p[4], vx4, za);                                             \
      za = fmaf(G0p[5], dppq<0xB1>(vx4), za);                                 \
      za = fmaf(G0p[6], dppq<0x4E>(vx4), za);                                 \
      za = fmaf(G0p[7], dppq<0x1B>(vx4), za);                                 \
      cur = tanh_fast(za);                                                    \
      hring[SL * 8 + l7] = cur;                                               \
    }                                                                         \
    {                                                                         \
      float* hn = hs[(TT) & 1];                                               \
      hn[0] = rdlane(cur, 0); hn[1] = rdlane(cur, 1);                         \
      hn[2] = rdlane(cur, 2); hn[3] = rdlane(cur, 3);                         \
      hn[4] = rdlane(cur, 4); hn[5] = rdlane(cur, 5);                         \
      hn[6] = rdlane(cur, 6); hn[7] = rdlane(cur, 7);                         \
      if (lane >= 8) {                                                        \
        float acc = fmaf(GcA[0], hn[0], seedC);                               \
        acc = fmaf(GcA[1], hn[1], acc); acc = fmaf(GcA[2], hn[2], acc);       \
        acc = fmaf(GcA[3], hn[3], acc); acc = fmaf(GcA[4], hn[4], acc);       \
        acc = fmaf(GcA[5], hn[5], acc); acc = fmaf(GcA[6], hn[6], acc);       \
        acc = fmaf(GcA[7], hn[7], acc);                                       \
        s2s[(TT) & 7] = sB;                                                   \
        *(float*)((char*)zacc + addrW[SL]) = acc;                             \
        chainpre = *(const float*)((char*)zacc + addrR[SL]);                  \
      }                                                                       \
    }                                                                         \
    if (lane < 16) {                                                          \
      zpP[(TT) & 1] = zacc[((SL + 2) & 15) * 8 + l7];                         \
      if ((TT) < 6) zbv[(TT) + 2] = basep[((SL + 2) & 15) * 8 + l7];          \
    }                                                                         \
  }

#define K4_HALF(BASE, DOFLUSH)                                                \
  {                                                                           \
    if (lane < 16) {                                                          \
      zbv[0] = basep[(BASE)*8 + l7];                                          \
      zbv[1] = basep[((BASE) + 1) * 8 + l7];                                  \
    }                                                                         \
    if (DOFLUSH) {                                                            \
      if (lane < 4) {                                                         \
        const float* fsrc = hring + ((BASE) ? 0 : 64) + lane * 16;            \
        float4* fdst = (float4*)(hflush + lane * 16);                         \
        fdst[0] = *(const float4*)(fsrc);                                     \
        fdst[1] = *(const float4*)(fsrc + 4);                                 \
        fdst[2] = *(const float4*)(fsrc + 8);                                 \
        fdst[3] = *(const float4*)(fsrc + 12);                                \
      }                                                                       \
      hflush += 64;                                                           \
    }                                                                         \
    QSTEP(BASE, 0) QSTEP(BASE, 1) QSTEP(BASE, 2) QSTEP(BASE, 3)               \
    QSTEP(BASE, 4) QSTEP(BASE, 5) QSTEP(BASE, 6) QSTEP(BASE, 7)               \
    __syncthreads();                                                          \
  }

__global__ __launch_bounds__(256, 1) void k4_core(
    const float* __restrict__ qbuf, const float* __restrict__ A8w,
    const float* __restrict__ Pws, const float* __restrict__ Gws,
    const float* __restrict__ Qws, float* __restrict__ hbuf,
    unsigned int* flagp) {
  const int tid = threadIdx.x;
  // 80KB guard: forces 1 block/CU so fillers never share block-0's CU.
  __shared__ float lds_guard[20480];
  if (flagp == (unsigned int*)0) lds_guard[tid] = 1.f;  // never true; keeps alloc

  // ---- DVFS-hold fillers: 4 dense waves, 8 indep FMA chains, poll/64 ----
  if (blockIdx.x != 0) {
    float x0 = 1.f, x1 = 1.01f, x2 = 1.02f, x3 = 1.03f;
    float x4 = 1.04f, x5 = 1.05f, x6 = 1.06f, x7 = 1.07f;
    for (int it = 0; it < 600000; ++it) {
      #pragma unroll
      for (int j = 0; j < 4; ++j) {
        x0 = fmaf(x0, 1.0000001f, 1e-30f);
        x1 = fmaf(x1, 0.9999999f, 1e-30f);
        x2 = fmaf(x2, 1.0000002f, 1e-30f);
        x3 = fmaf(x3, 0.9999998f, 1e-30f);
        x4 = fmaf(x4, 1.0000003f, 1e-30f);
        x5 = fmaf(x5, 0.9999997f, 1e-30f);
        x6 = fmaf(x6, 1.0000004f, 1e-30f);
        x7 = fmaf(x7, 0.9999996f, 1e-30f);
      }
      if ((it & 63) == 0) {
        if (__hip_atomic_load(flagp, __ATOMIC_RELAXED,
                              __HIP_MEMORY_SCOPE_AGENT) != 0u)
          break;
      }
    }
    asm volatile("" ::"v"(x0), "v"(x1), "v"(x2), "v"(x3), "v"(x4), "v"(x5),
                 "v"(x6), "v"(x7));
    return;
  }

  __shared__ __align__(16) float zacc[16 * 8 + 8];  // conv chain plane + dummy0
  __shared__ __align__(16) float basep[16 * 8];     // base plane (wave 2)
  __shared__ __align__(16) float hring[16 * 8];
  __shared__ __align__(16) float rbuf[2][100];
  const int wave = tid >> 6;
  const int lane = tid & 63;

  for (int i = tid; i < 136; i += 256) zacc[i] = 0.f;
  for (int i = tid; i < 128; i += 256) hring[i] = 0.f;
  if (tid < 200) ((float*)rbuf)[tid] = 0.f;

  if (wave == 0) {
    __builtin_amdgcn_s_setprio(1);
    const int l7 = lane & 7;
    const int g = (lane >> 3) - 1;  // conv group 0..6 for lanes 8..63
    const int ci = lane & 7;
    float G0p[8];
    float GcA[8], GcB[8];
    int addrW[16], addrR[16];
    if (lane < 16) {
      #pragma unroll
      for (int o = 0; o < 8; ++o) G0p[o] = Gws[l7 * 8 + (l7 ^ o)];
    }
    if (lane >= 8) {
      const int kA = 1 + g;  // taps 1..7
      const int kB = 8 + g;  // taps 8..14 (6-step reg pipe + 1-step-late calc)
      #pragma unroll
      for (int c = 0; c < 8; ++c) {
        GcA[c] = Gws[kA * 64 + ci * 8 + c];
        GcB[c] = Gws[kB * 64 + ci * 8 + c];
      }
      #pragma unroll
      for (int k = 0; k < 16; ++k)
        addrW[k] = (((k + 2 + g) & 15) * 8 + ci) * 4;
      #pragma unroll
      for (int k = 0; k < 16; ++k)
        addrR[k] = (g == 6) ? (128 + ci) * 4 : addrW[(k + 1) & 15];
    }
    __syncthreads();  // matches other waves' init barrier

    float cur = 0.f, chainpre = 0.f;
    float zpP[2];
    float zbv[8];
    float s2s[8];
    float hs[2][8];
    zpP[0] = 0.f;
    zpP[1] = 0.f;
    #pragma unroll
    for (int j = 0; j < 8; ++j) {
      zbv[j] = 0.f; s2s[j] = 0.f; hs[0][j] = 0.f; hs[1][j] = 0.f;
    }
    float* hflush = hbuf;

    K4_HALF(0, 0)
    K4_HALF(8, 1)
    for (int mm = 1; mm < 4096; ++mm) {
      K4_HALF(0, 1)
      K4_HALF(8, 1)
    }
    if (lane < 4) {  // flush h of final block (8191, ring half 1)
      const float* fsrc = hring + 64 + lane * 16;
      float4* fdst = (float4*)(hflush + lane * 16);
      fdst[0] = *(const float4*)(fsrc);
      fdst[1] = *(const float4*)(fsrc + 4);
      fdst[2] = *(const float4*)(fsrc + 8);
      fdst[3] = *(const float4*)(fsrc + 12);
    }
  } else if (wave == 1 || wave == 3) {
    // ---- r-advance: r_m = A^8 r_{m-1} + sum_i Q_i h[(m-1)*8+i] ----
    // LDS-lean: scatter loads + v_readlane broadcasts (literal lanes).
    const int rrow = (wave == 1) ? lane : 64 + lane;
    float A8row[100];
    float Qrow[64];
    if (rrow < 100) {
      #pragma unroll
      for (int i = 0; i < 25; ++i)
        *(float4*)&A8row[4 * i] = ((const float4*)(A8w + rrow * 100))[i];
      #pragma unroll
      for (int i = 0; i < 8; ++i)
        #pragma unroll
        for (int c = 0; c < 8; ++c) Qrow[i * 8 + c] = Qws[i * 800 + rrow * 8 + c];
    }
    const int hi_idx = 64 + (lane < 36 ? lane : 35);
    __syncthreads();
    for (int m = 0; m < 8192; ++m) {
      const int prev = (m + 1) & 1;
      float r_lo = rbuf[prev][lane];
      float r_hi = rbuf[prev][hi_idx];
      float h_my = hring[((m - 1) & 1) * 64 + lane];
      float p[4] = {0.f, 0.f, 0.f, 0.f};
      #pragma unroll
      for (int c = 0; c < 100; ++c) {
        float s = (c < 64) ? rdlane(r_lo, c) : rdlane(r_hi, c - 64);
        p[c & 3] = fmaf(A8row[c], s, p[c & 3]);
      }
      float q[4] = {0.f, 0.f, 0.f, 0.f};
      #pragma unroll
      for (int j = 0; j < 64; ++j) {
        float s = rdlane(h_my, j);
        q[j & 3] = fmaf(Qrow[j], s, q[j & 3]);
      }
      if (rrow < 100)
        rbuf[m & 1][rrow] =
            ((p[0] + p[1]) + (p[2] + p[3])) + ((q[0] + q[1]) + (q[2] + q[3]));
      __syncthreads();
    }
  } else {
    // ---- wave 2: base plane for block m+1 = q + P_{16+j} r_{m-1} + G-terms
    // base covers G-indices [15..15+wj] (entries jj>wj zeroed); conv owns
    // [8..14] unmasked. LDS-lean broadcasts as in waves 1/3; qbuf reads via
    // 4-deep register prefetch (global, not LDS).
    const int wj = lane >> 3, wi = lane & 7;
    float Prow[100];
    float Gw2[64];
    #pragma unroll
    for (int i = 0; i < 25; ++i)
      *(float4*)&Prow[4 * i] = ((const float4*)(Pws + wj * 800 + wi * 100))[i];
    #pragma unroll
    for (int jj = 0; jj < 8; ++jj)
      #pragma unroll
      for (int c = 0; c < 8; ++c)
        Gw2[jj * 8 + c] =
            (jj > wj) ? 0.f : Gws[(15 + wj - jj) * 64 + wi * 8 + c];
    float qpipe[4];
    #pragma unroll
    for (int i = 0; i < 4; ++i)
      qpipe[i] = qbuf[(size_t)((i + 1) * 8 + wj) * 8 + wi];
    basep[wj * 8 + wi] = qbuf[wj * 8 + wi];  // block-0 base = q
    const int hi_idx = 64 + (lane < 36 ? lane : 35);
    __syncthreads();
    for (int mo = 0; mo < 2048; ++mo) {
      #pragma unroll
      for (int mi = 0; mi < 4; ++mi) {
        const int m = mo * 4 + mi;
        float qv = qpipe[mi];
        int mp = m + 5;
        if (mp > 8192) mp = 8192;
        qpipe[mi] = qbuf[(size_t)(mp * 8 + wj) * 8 + wi];
        const int prev = (mi + 1) & 1;
        float r_lo = rbuf[prev][lane];
        float r_hi = rbuf[prev][hi_idx];
        float h_my = hring[((mi + 1) & 1) * 64 + lane];
        float p[4] = {0.f, 0.f, 0.f, 0.f};
        #pragma unroll
        for (int c = 0; c < 100; ++c) {
          float s = (c < 64) ? rdlane(r_lo, c) : rdlane(r_hi, c - 64);
          p[c & 3] = fmaf(Prow[c], s, p[c & 3]);
        }
        float gg[4] = {0.f, 0.f, 0.f, 0.f};
        #pragma unroll
        for (int j = 0; j < 64; ++j) {
          float s = rdlane(h_my, j);
          gg[j & 3] = fmaf(Gw2[j], s, gg[j & 3]);
        }
        basep[(((mi + 1) & 1) * 8 + wj) * 8 + wi] =
            qv + ((p[0] + p[1]) + (p[2] + p[3])) +
            ((gg[0] + gg[1]) + (gg[2] + gg[3]));
        __syncthreads();
      }
    }
  }

  // ---- all of block 0 done: release the fillers ----
  __syncthreads();
  if (tid == 0)
    __hip_atomic_store(flagp, 1u, __ATOMIC_RELAXED, __HIP_MEMORY_SCOPE_AGENT);
}

// ---------- launch ----------
extern "C" void kernel_launch(void* const* d_in, const int* in_sizes, int n_in,
                              void* d_out, int out_size, void* d_ws, size_t ws_size,
                              hipStream_t stream) {
  const float* c0 = (const float*)d_in[0];
  const float* w  = (const float*)d_in[1];
  const float* u  = (const float*)d_in[2];
  const float* A  = (const float*)d_in[3];
  const float* Bw = (const float*)d_in[4];
  const float* W1 = (const float*)d_in[5];
  const float* b1 = (const float*)d_in[6];
  const float* W2 = (const float*)d_in[7];
  const float* b2 = (const float*)d_in[8];
  const int* obs  = (const int*)d_in[9];
  float* out_c = (float*)d_out;
  float* out_y = out_c + (size_t)T_STEPS * SD;

  float* wsf = (float*)d_ws;
  float* A8    = wsf;                 // 10000
  float* A256  = wsf + 10000;         // 10000
  float* Pws   = wsf + 20000;         // 8*800
  float* Gws   = wsf + 26400;         // 23*64
  float* Qws   = wsf + 27872;         // 8*800
  float* Send  = wsf + 34272;         // 256*100 (dead after k_scan -> flag)
  float* X     = wsf + 59872;         // 256*100
  float* qbuf  = wsf + 85472;         // (T+16)*8
  float* hbuf  = wsf + 609888;        // T*8 + 64
  float* SendR = wsf + 1134240;       // 256*100
  float* XR    = wsf + 1159840;       // 256*100

  hipLaunchKernelGGL(k0_setup, dim3(1), dim3(256), 0, stream,
                     A, W1, W2, A8, A256, Pws, Gws, Qws);
  hipLaunchKernelGGL(k_rollout<0>, dim3(256), dim3(256), 0, stream,
                     A, Bw, b2, u, w, (const float*)nullptr, (const float*)nullptr,
                     (const float*)nullptr, (const float*)nullptr, (const float*)nullptr,
                     (const float*)nullptr, Send, (float*)nullptr, (float*)nullptr,
                     (const int*)nullptr, (float*)nullptr);
  hipLaunchKernelGGL(k_scan, dim3(1), dim3(256), 0, stream, A256, Send, c0, 1, X);
  hipLaunchKernelGGL(k_rollout<1>, dim3(256), dim3(256), 0, stream,
                     A, Bw, b2, u, w, (const float*)nullptr, (const float*)nullptr,
                     W1, b1, c0, X, (float*)nullptr, out_c, qbuf,
                     (const int*)nullptr, (float*)nullptr);
  // Send is dead now (consumed by k_scan). Reuse its first word as the
  // filler release flag for k4_core.
  hipMemsetAsync(Send, 0, sizeof(unsigned int), stream);
  hipLaunchKernelGGL(k4_core, dim3(256), dim3(256), 0, stream,
                     qbuf, A8, Pws, Gws, Qws, hbuf, (unsigned int*)Send);
  hipLaunchKernelGGL(k_rollout<2>, dim3(256), dim3(256), 0, stream,
                     A, (const float*)nullptr, (const float*)nullptr,
                     (const float*)nullptr, (const float*)nullptr, W2, hbuf,
                     (const float*)nullptr, (const float*)nullptr, (const float*)nullptr,
                     (const float*)nullptr, SendR, (float*)nullptr, (float*)nullptr,
                     (const int*)nullptr, (float*)nullptr);
  hipLaunchKernelGGL(k_scan, dim3(1), dim3(256), 0, stream, A256, SendR,
                     (const float*)nullptr, 0, XR);
  hipLaunchKernelGGL(k_rollout<3>, dim3(256), dim3(256), 0, stream,
                     A, (const float*)nullptr, (const float*)nullptr,
                     (const float*)nullptr, (const float*)nullptr, W2, hbuf,
                     (const float*)nullptr, (const float*)nullptr, (const float*)nullptr,
                     XR, (float*)nullptr, out_c, (float*)nullptr, obs, out_y);
}